// Round 1
// baseline (523.719 us; speedup 1.0000x reference)
//
#include <hip/hip_runtime.h>

// Problem constants
#define NP 2048          // B*H1*W1 points
#define CD 768           // channels
#define MMD_GAMMA 0.00065f

// Workspace layout (bytes):
//   [0, 24)        : double acc[3]  (kxx_sum, kyy_sum, kxy_sum)
//   [1024, +2MB)   : double d2p[8][2048][16]  partial d2 per c-split
//   X   : float[2048*768]
//   Ysel: float[2048*768]
//   a2  : float[2048]
//   b2  : float[2048]
// total ~14.7 MB

// ---------------------------------------------------------------------------
// Transpose x (B,C,32,32) -> X (N=2048, C=768) row-major, coalesced both ways
__global__ void k_transpose_x(const float* __restrict__ x, float* __restrict__ X) {
    __shared__ float tile[64][33];
    int bx = blockIdx.x;               // 0..63 = b*32 + h1
    int c0 = blockIdx.y * 64;          // c tile (12 tiles of 64)
    int b = bx >> 5, h1 = bx & 31;
    int tid = threadIdx.x;
    const float* src = x + (size_t)(b * 768 + c0) * 1024 + h1 * 32;
    #pragma unroll
    for (int p = 0; p < 8; ++p) {
        int cl = p * 8 + (tid >> 5);
        int w1 = tid & 31;
        tile[cl][w1] = src[(size_t)cl * 1024 + w1];
    }
    __syncthreads();
    int n0 = bx * 32;
    #pragma unroll
    for (int p = 0; p < 8; ++p) {
        int w1 = p * 4 + (tid >> 6);
        int c  = tid & 63;
        X[(size_t)(n0 + w1) * CD + c0 + c] = tile[c][w1];
    }
}

// ---------------------------------------------------------------------------
// Partial d2: for each (n, cand) accumulate sum_c (x - y)^2 in fp64.
// grid (64, 8): blockIdx.x = b*32+h1, blockIdx.y = c-split (96 channels each).
// Threads: col = tid&127 covers 128 y-columns of the 4-row band; tid>>7 picks
// row parity. Fully coalesced y reads (512B per row segment).
__global__ void k_d2_partial(const float* __restrict__ x, const float* __restrict__ y,
                             double* __restrict__ d2p) {
    __shared__ float xs[8][32];
    int bx = blockIdx.x;
    int cs = blockIdx.y;
    int b = bx >> 5, h1 = bx & 31;
    int tid = threadIdx.x;
    int col = tid & 127;
    int half = tid >> 7;           // 0/1
    double acc0 = 0.0, acc1 = 0.0;
    int cbase = cs * 96;
    for (int c0 = cbase; c0 < cbase + 96; c0 += 8) {
        __syncthreads();
        {
            int cl = tid >> 5, w1 = tid & 31;
            xs[cl][w1] = x[(size_t)(b * 768 + c0 + cl) * 1024 + h1 * 32 + w1];
        }
        __syncthreads();
        #pragma unroll
        for (int cl = 0; cl < 8; ++cl) {
            float xv = xs[cl][col >> 2];
            size_t ybase = (size_t)(b * 768 + c0 + cl) * 16384;
            {
                int row = 4 * h1 + half;            // i = half
                float yv = y[ybase + (size_t)row * 128 + col];
                double d = (double)xv - (double)yv;
                acc0 += d * d;
            }
            {
                int row = 4 * h1 + 2 + half;        // i = 2+half
                float yv = y[ybase + (size_t)row * 128 + col];
                double d = (double)xv - (double)yv;
                acc1 += d * d;
            }
        }
    }
    int w1 = col >> 2, j = col & 3;
    int n = (b * 32 + h1) * 32 + w1;
    d2p[((size_t)cs * NP + n) * 16 + half * 4 + j]       = acc0;
    d2p[((size_t)cs * NP + n) * 16 + (2 + half) * 4 + j] = acc1;
}

// ---------------------------------------------------------------------------
// Reduce 8 partials per (n,cand), argmax (first-max ties like np.argmax),
// gather selected y row into Ysel (coalesced write; scattered reads hit L3).
__global__ void k_argmax_gather(const double* __restrict__ d2p, const float* __restrict__ y,
                                float* __restrict__ Ysel) {
    __shared__ double sd2[16];
    __shared__ int sidx;
    int n = blockIdx.x;
    int tid = threadIdx.x;
    if (tid < 16) {
        double s = 0.0;
        #pragma unroll
        for (int cs = 0; cs < 8; ++cs) s += d2p[((size_t)cs * NP + n) * 16 + tid];
        sd2[tid] = s;
    }
    __syncthreads();
    if (tid == 0) {
        double best = sd2[0]; int bi = 0;
        #pragma unroll
        for (int k = 1; k < 16; ++k) if (sd2[k] > best) { best = sd2[k]; bi = k; }
        sidx = bi;
    }
    __syncthreads();
    int idx = sidx;
    int b = n >> 10, rem = n & 1023, h1 = rem >> 5, w1 = rem & 31;
    int row = 4 * h1 + (idx >> 2);
    int colp = 4 * w1 + (idx & 3);
    for (int c = tid; c < CD; c += 256) {
        float v = y[(size_t)(b * 768 + c) * 16384 + (size_t)row * 128 + colp];
        Ysel[(size_t)n * CD + c] = v;
    }
}

// ---------------------------------------------------------------------------
// Row squared norms
__global__ void k_row_norm(const float* __restrict__ M, float* __restrict__ out) {
    __shared__ double red[256];
    int n = blockIdx.x, tid = threadIdx.x;
    double s = 0.0;
    for (int c = tid; c < CD; c += 256) {
        float v = M[(size_t)n * CD + c];
        s += (double)v * (double)v;
    }
    red[tid] = s;
    __syncthreads();
    for (int st = 128; st > 0; st >>= 1) {
        if (tid < st) red[tid] += red[tid + st];
        __syncthreads();
    }
    if (tid == 0) out[n] = (float)red[0];
}

// ---------------------------------------------------------------------------
// MMD Gram kernel: 64x64 pair tile per block, BK=16, 4x4 per thread, fp32.
// z=0: (X,X) -> acc[0]; z=1: (Y,Y) -> acc[1]; z=2: (X,Y) -> acc[2].
__global__ void k_mmd(const float* __restrict__ X, const float* __restrict__ Y,
                      const float* __restrict__ a2, const float* __restrict__ b2,
                      double* __restrict__ acc) {
    __shared__ __align__(16) float As[16 * 68];
    __shared__ __align__(16) float Bs[16 * 68];
    __shared__ double red[256];
    int z = blockIdx.z;
    const float* A  = (z == 1) ? Y : X;
    const float* B  = (z == 0) ? X : Y;
    const float* na = (z == 1) ? b2 : a2;
    const float* nb = (z == 0) ? a2 : b2;
    int i0 = blockIdx.y * 64, j0 = blockIdx.x * 64;
    int tid = threadIdx.x;
    int tx = tid & 15, ty = tid >> 4;
    int lr = tid >> 2;              // 0..63: tile row for staging
    int lk = (tid & 3) * 4;         // k quad for staging
    float accm[4][4] = {};
    for (int k0 = 0; k0 < CD; k0 += 16) {
        __syncthreads();
        float4 a4 = *(const float4*)(A + (size_t)(i0 + lr) * CD + k0 + lk);
        float4 b4 = *(const float4*)(B + (size_t)(j0 + lr) * CD + k0 + lk);
        As[(lk + 0) * 68 + lr] = a4.x; As[(lk + 1) * 68 + lr] = a4.y;
        As[(lk + 2) * 68 + lr] = a4.z; As[(lk + 3) * 68 + lr] = a4.w;
        Bs[(lk + 0) * 68 + lr] = b4.x; Bs[(lk + 1) * 68 + lr] = b4.y;
        Bs[(lk + 2) * 68 + lr] = b4.z; Bs[(lk + 3) * 68 + lr] = b4.w;
        __syncthreads();
        #pragma unroll
        for (int k = 0; k < 16; ++k) {
            float4 av = *(const float4*)&As[k * 68 + ty * 4];
            float4 bv = *(const float4*)&Bs[k * 68 + tx * 4];
            float va[4] = {av.x, av.y, av.z, av.w};
            float vb[4] = {bv.x, bv.y, bv.z, bv.w};
            #pragma unroll
            for (int u = 0; u < 4; ++u)
                #pragma unroll
                for (int v = 0; v < 4; ++v)
                    accm[u][v] += va[u] * vb[v];
        }
    }
    float s = 0.0f;
    #pragma unroll
    for (int u = 0; u < 4; ++u) {
        float ai = na[i0 + ty * 4 + u];
        #pragma unroll
        for (int v = 0; v < 4; ++v) {
            float bj = nb[j0 + tx * 4 + v];
            float d = ai + bj - 2.0f * accm[u][v];
            d = fmaxf(d, 0.0f);
            s += expf(-MMD_GAMMA * d);
        }
    }
    red[tid] = (double)s;
    __syncthreads();
    for (int st = 128; st > 0; st >>= 1) {
        if (tid < st) red[tid] += red[tid + st];
        __syncthreads();
    }
    if (tid == 0) atomicAdd(&acc[z], red[0]);
}

// ---------------------------------------------------------------------------
__global__ void k_finalize(const double* __restrict__ acc, float* __restrict__ out) {
    const double inv = 1.0 / ((double)NP * (double)NP);
    out[0] = (float)((acc[0] + acc[1] - 2.0 * acc[2]) * inv);
}

extern "C" void kernel_launch(void* const* d_in, const int* in_sizes, int n_in,
                              void* d_out, int out_size, void* d_ws, size_t ws_size,
                              hipStream_t stream) {
    const float* x = (const float*)d_in[0];
    const float* y = (const float*)d_in[1];
    float* out = (float*)d_out;

    char* ws = (char*)d_ws;
    double* acc  = (double*)ws;                       // 3 doubles
    double* d2p  = (double*)(ws + 1024);              // 8*2048*16 doubles = 2 MB
    float*  X    = (float*)(ws + 1024 + 2097152);
    float*  Ysel = X + (size_t)NP * CD;
    float*  a2   = Ysel + (size_t)NP * CD;
    float*  b2   = a2 + NP;

    hipMemsetAsync(acc, 0, 3 * sizeof(double), stream);
    k_transpose_x<<<dim3(64, 12), 256, 0, stream>>>(x, X);
    k_d2_partial<<<dim3(64, 8), 256, 0, stream>>>(x, y, d2p);
    k_argmax_gather<<<NP, 256, 0, stream>>>(d2p, y, Ysel);
    k_row_norm<<<NP, 256, 0, stream>>>(X, a2);
    k_row_norm<<<NP, 256, 0, stream>>>(Ysel, b2);
    k_mmd<<<dim3(32, 32, 3), 256, 0, stream>>>(X, Ysel, a2, b2, acc);
    k_finalize<<<1, 1, 0, stream>>>(acc, out);
}

// Round 2
// 339.369 us; speedup vs baseline: 1.5432x; 1.5432x over previous
//
#include <hip/hip_runtime.h>

// Problem constants
#define NP 2048          // B*H1*W1 points
#define CD 768           // channels
#define MMD_GAMMA 0.00065f

typedef short bf16frag __attribute__((ext_vector_type(8)));
typedef float f32x4 __attribute__((ext_vector_type(4)));

// Workspace layout (bytes):
//   [0, 24)               : double acc[3]
//   [1024, +2MB)          : double d2p[8][2048][16]
//   X    : float[2048*768]      (row-major points)
//   Ysel : float[2048*768]
//   a2,b2: float[2048] each
//   Xhi,Xlo,Yhi,Ylo : ushort[2048*768] each (bf16 split halves)
// total ~27.3 MB

// ---------------------------------------------------------------------------
__global__ void k_transpose_x(const float* __restrict__ x, float* __restrict__ X) {
    __shared__ float tile[64][33];
    int bx = blockIdx.x;
    int c0 = blockIdx.y * 64;
    int b = bx >> 5, h1 = bx & 31;
    int tid = threadIdx.x;
    const float* src = x + (size_t)(b * 768 + c0) * 1024 + h1 * 32;
    #pragma unroll
    for (int p = 0; p < 8; ++p) {
        int cl = p * 8 + (tid >> 5);
        int w1 = tid & 31;
        tile[cl][w1] = src[(size_t)cl * 1024 + w1];
    }
    __syncthreads();
    int n0 = bx * 32;
    #pragma unroll
    for (int p = 0; p < 8; ++p) {
        int w1 = p * 4 + (tid >> 6);
        int c  = tid & 63;
        X[(size_t)(n0 + w1) * CD + c0 + c] = tile[c][w1];
    }
}

// ---------------------------------------------------------------------------
__global__ void k_d2_partial(const float* __restrict__ x, const float* __restrict__ y,
                             double* __restrict__ d2p) {
    __shared__ float xs[8][32];
    int bx = blockIdx.x;
    int cs = blockIdx.y;
    int b = bx >> 5, h1 = bx & 31;
    int tid = threadIdx.x;
    int col = tid & 127;
    int half = tid >> 7;
    double acc0 = 0.0, acc1 = 0.0;
    int cbase = cs * 96;
    for (int c0 = cbase; c0 < cbase + 96; c0 += 8) {
        __syncthreads();
        {
            int cl = tid >> 5, w1 = tid & 31;
            xs[cl][w1] = x[(size_t)(b * 768 + c0 + cl) * 1024 + h1 * 32 + w1];
        }
        __syncthreads();
        #pragma unroll
        for (int cl = 0; cl < 8; ++cl) {
            float xv = xs[cl][col >> 2];
            size_t ybase = (size_t)(b * 768 + c0 + cl) * 16384;
            {
                int row = 4 * h1 + half;
                float yv = y[ybase + (size_t)row * 128 + col];
                double d = (double)xv - (double)yv;
                acc0 += d * d;
            }
            {
                int row = 4 * h1 + 2 + half;
                float yv = y[ybase + (size_t)row * 128 + col];
                double d = (double)xv - (double)yv;
                acc1 += d * d;
            }
        }
    }
    int w1 = col >> 2, j = col & 3;
    int n = (b * 32 + h1) * 32 + w1;
    d2p[((size_t)cs * NP + n) * 16 + half * 4 + j]       = acc0;
    d2p[((size_t)cs * NP + n) * 16 + (2 + half) * 4 + j] = acc1;
}

// ---------------------------------------------------------------------------
__global__ void k_argmax_gather(const double* __restrict__ d2p, const float* __restrict__ y,
                                float* __restrict__ Ysel) {
    __shared__ double sd2[16];
    __shared__ int sidx;
    int n = blockIdx.x;
    int tid = threadIdx.x;
    if (tid < 16) {
        double s = 0.0;
        #pragma unroll
        for (int cs = 0; cs < 8; ++cs) s += d2p[((size_t)cs * NP + n) * 16 + tid];
        sd2[tid] = s;
    }
    __syncthreads();
    if (tid == 0) {
        double best = sd2[0]; int bi = 0;
        #pragma unroll
        for (int k = 1; k < 16; ++k) if (sd2[k] > best) { best = sd2[k]; bi = k; }
        sidx = bi;
    }
    __syncthreads();
    int idx = sidx;
    int b = n >> 10, rem = n & 1023, h1 = rem >> 5, w1 = rem & 31;
    int row = 4 * h1 + (idx >> 2);
    int colp = 4 * w1 + (idx & 3);
    for (int c = tid; c < CD; c += 256) {
        float v = y[(size_t)(b * 768 + c) * 16384 + (size_t)row * 128 + colp];
        Ysel[(size_t)n * CD + c] = v;
    }
}

// ---------------------------------------------------------------------------
__global__ void k_row_norm(const float* __restrict__ M, float* __restrict__ out) {
    __shared__ double red[256];
    int n = blockIdx.x, tid = threadIdx.x;
    double s = 0.0;
    for (int c = tid; c < CD; c += 256) {
        float v = M[(size_t)n * CD + c];
        s += (double)v * (double)v;
    }
    red[tid] = s;
    __syncthreads();
    for (int st = 128; st > 0; st >>= 1) {
        if (tid < st) red[tid] += red[tid + st];
        __syncthreads();
    }
    if (tid == 0) out[n] = (float)red[0];
}

// ---------------------------------------------------------------------------
// Split fp32 -> (hi, lo) bf16 halves for X and Ysel.
static __device__ inline unsigned short f2bf(float v) {
    union { float f; unsigned u; } a; a.f = v;
    unsigned r = a.u + 0x7fffu + ((a.u >> 16) & 1u);
    return (unsigned short)(r >> 16);
}
static __device__ inline float bf2f(unsigned short h) {
    union { unsigned u; float f; } a; a.u = ((unsigned)h) << 16;
    return a.f;
}
__global__ void k_pack(const float* __restrict__ X, const float* __restrict__ Ysel,
                       unsigned short* __restrict__ Xhi, unsigned short* __restrict__ Xlo,
                       unsigned short* __restrict__ Yhi, unsigned short* __restrict__ Ylo) {
    int z = blockIdx.y;
    const float* src = z ? Ysel : X;
    unsigned short* dh = z ? Yhi : Xhi;
    unsigned short* dl = z ? Ylo : Xlo;
    size_t i4 = ((size_t)blockIdx.x * 256 + threadIdx.x) * 4;
    float4 v = *(const float4*)(src + i4);
    ushort4 h, l;
    h.x = f2bf(v.x); l.x = f2bf(v.x - bf2f(h.x));
    h.y = f2bf(v.y); l.y = f2bf(v.y - bf2f(h.y));
    h.z = f2bf(v.z); l.z = f2bf(v.z - bf2f(h.z));
    h.w = f2bf(v.w); l.w = f2bf(v.w - bf2f(h.w));
    *(ushort4*)(dh + i4) = h;
    *(ushort4*)(dl + i4) = l;
}

// ---------------------------------------------------------------------------
// MFMA Gram + exp-sum. Split-bf16: K'' = 3*768, A-side = [hi|lo|hi],
// B-side = [hi|hi|lo] (phase-dependent source arrays; BK=64 divides 768 so
// no window straddles a phase boundary).
// Grid: 136 (XX upper-tri blocks) + 136 (YY) + 256 (XY full) = 528 blocks.
__global__ __launch_bounds__(256, 2)
void k_mmd_mfma(const unsigned short* __restrict__ Xhi, const unsigned short* __restrict__ Xlo,
                const unsigned short* __restrict__ Yhi, const unsigned short* __restrict__ Ylo,
                const float* __restrict__ a2, const float* __restrict__ b2,
                double* __restrict__ accg) {
    __shared__ unsigned short As[128 * 72];   // rows padded to 72 bf16 (144B)
    __shared__ unsigned short Bs[128 * 72];
    __shared__ double red[256];

    int id = blockIdx.x;
    int z, bx, by;
    double w = 1.0;
    if (id < 272) {
        z = (id < 136) ? 0 : 1;
        if (id >= 136) id -= 136;
        int r = 0;
        while (id >= 16 - r) { id -= 16 - r; ++r; }
        by = r; bx = r + id;
        if (bx != by) w = 2.0;
    } else {
        z = 2; id -= 272;
        bx = id & 15; by = id >> 4;
    }
    const unsigned short* AH = (z == 1) ? Yhi : Xhi;
    const unsigned short* AL = (z == 1) ? Ylo : Xlo;
    const unsigned short* BH = (z == 0) ? Xhi : Yhi;
    const unsigned short* BL = (z == 0) ? Xlo : Ylo;
    const float* na = (z == 1) ? b2 : a2;
    const float* nb = (z == 0) ? a2 : b2;
    int i0 = by * 128, j0 = bx * 128;

    int tid = threadIdx.x;
    int lane = tid & 63;
    int wv = tid >> 6;
    int wr = wv >> 1, wc = wv & 1;
    int m = lane & 15, q = lane >> 4;
    int srow = tid >> 3, sg = tid & 7;

    f32x4 acc[4][4] = {};

    for (int kk = 0; kk < 2304; kk += 64) {
        int p = (kk >= 1536) ? 2 : (kk >= 768 ? 1 : 0);
        int kc = kk - p * 768;
        const unsigned short* Asrc = (p == 1) ? AL : AH;
        const unsigned short* Bsrc = (p == 2) ? BL : BH;
        __syncthreads();
        #pragma unroll
        for (int s = 0; s < 4; ++s) {
            int r = s * 32 + srow;
            uint4 av = *(const uint4*)(Asrc + (size_t)(i0 + r) * CD + kc + sg * 8);
            uint4 bv = *(const uint4*)(Bsrc + (size_t)(j0 + r) * CD + kc + sg * 8);
            *(uint4*)&As[r * 72 + sg * 8] = av;
            *(uint4*)&Bs[r * 72 + sg * 8] = bv;
        }
        __syncthreads();
        #pragma unroll
        for (int s16 = 0; s16 < 2; ++s16) {
            bf16frag af[4], bg[4];
            #pragma unroll
            for (int t = 0; t < 4; ++t) {
                af[t] = *(const bf16frag*)&As[(wr * 64 + t * 16 + m) * 72 + s16 * 32 + q * 8];
                bg[t] = *(const bf16frag*)&Bs[(wc * 64 + t * 16 + m) * 72 + s16 * 32 + q * 8];
            }
            #pragma unroll
            for (int ti = 0; ti < 4; ++ti)
                #pragma unroll
                for (int tj = 0; tj < 4; ++tj)
                    acc[ti][tj] = __builtin_amdgcn_mfma_f32_16x16x32_bf16(
                        af[ti], bg[tj], acc[ti][tj], 0, 0, 0);
        }
    }

    // Epilogue: C[row][col], row = q*4 + reg (A-side i), col = m (B-side j)
    double s = 0.0;
    #pragma unroll
    for (int ti = 0; ti < 4; ++ti) {
        #pragma unroll
        for (int r = 0; r < 4; ++r) {
            int i = i0 + wr * 64 + ti * 16 + q * 4 + r;
            float ai = na[i];
            #pragma unroll
            for (int tj = 0; tj < 4; ++tj) {
                int j = j0 + wc * 64 + tj * 16 + m;
                float d = ai + nb[j] - 2.0f * acc[ti][tj][r];
                d = fmaxf(d, 0.0f);
                s += (double)expf(-MMD_GAMMA * d);
            }
        }
    }
    red[tid] = s;
    __syncthreads();
    for (int st = 128; st > 0; st >>= 1) {
        if (tid < st) red[tid] += red[tid + st];
        __syncthreads();
    }
    if (tid == 0) atomicAdd(&accg[z], w * red[0]);
}

// ---------------------------------------------------------------------------
__global__ void k_finalize(const double* __restrict__ acc, float* __restrict__ out) {
    const double inv = 1.0 / ((double)NP * (double)NP);
    out[0] = (float)((acc[0] + acc[1] - 2.0 * acc[2]) * inv);
}

extern "C" void kernel_launch(void* const* d_in, const int* in_sizes, int n_in,
                              void* d_out, int out_size, void* d_ws, size_t ws_size,
                              hipStream_t stream) {
    const float* x = (const float*)d_in[0];
    const float* y = (const float*)d_in[1];
    float* out = (float*)d_out;

    char* ws = (char*)d_ws;
    double* acc  = (double*)ws;                       // 3 doubles
    double* d2p  = (double*)(ws + 1024);              // 2 MB
    float*  X    = (float*)(ws + 1024 + 2097152);
    float*  Ysel = X + (size_t)NP * CD;
    float*  a2   = Ysel + (size_t)NP * CD;
    float*  b2   = a2 + NP;
    unsigned short* Xhi = (unsigned short*)(b2 + NP);
    unsigned short* Xlo = Xhi + (size_t)NP * CD;
    unsigned short* Yhi = Xlo + (size_t)NP * CD;
    unsigned short* Ylo = Yhi + (size_t)NP * CD;

    hipMemsetAsync(acc, 0, 3 * sizeof(double), stream);
    k_transpose_x<<<dim3(64, 12), 256, 0, stream>>>(x, X);
    k_d2_partial<<<dim3(64, 8), 256, 0, stream>>>(x, y, d2p);
    k_argmax_gather<<<NP, 256, 0, stream>>>(d2p, y, Ysel);
    k_row_norm<<<NP, 256, 0, stream>>>(X, a2);
    k_row_norm<<<NP, 256, 0, stream>>>(Ysel, b2);
    k_pack<<<dim3(1536, 2), 256, 0, stream>>>(X, Ysel, Xhi, Xlo, Yhi, Ylo);
    k_mmd_mfma<<<528, 256, 0, stream>>>(Xhi, Xlo, Yhi, Ylo, a2, b2, acc);
    k_finalize<<<1, 1, 0, stream>>>(acc, out);
}

// Round 3
// 270.519 us; speedup vs baseline: 1.9360x; 1.2545x over previous
//
#include <hip/hip_runtime.h>

// Problem constants
#define NP 2048          // B*H1*W1 points
#define CD 768           // channels
#define NSPLIT 6         // channel splits for d2 partials (128 ch each)
#define MMD_GAMMA 0.00065f

typedef short bf16frag __attribute__((ext_vector_type(8)));
typedef float f32x4 __attribute__((ext_vector_type(4)));

// Workspace layout (bytes):
//   [0, 24)               : double acc[3]
//   [1024, +2MB)          : double d2p[NSPLIT][2048][16]
//   X    : float[2048*768]
//   Ysel : float[2048*768]
//   a2,b2: float[2048] each
//   Xhi,Xlo,Yhi,Ylo : ushort[2048*768] each (bf16 split halves)

// ---------------------------------------------------------------------------
__global__ void k_transpose_x(const float* __restrict__ x, float* __restrict__ X) {
    __shared__ float tile[64][33];
    int bx = blockIdx.x;
    int c0 = blockIdx.y * 64;
    int b = bx >> 5, h1 = bx & 31;
    int tid = threadIdx.x;
    const float* src = x + (size_t)(b * 768 + c0) * 1024 + h1 * 32;
    #pragma unroll
    for (int p = 0; p < 8; ++p) {
        int cl = p * 8 + (tid >> 5);
        int w1 = tid & 31;
        tile[cl][w1] = src[(size_t)cl * 1024 + w1];
    }
    __syncthreads();
    int n0 = bx * 32;
    #pragma unroll
    for (int p = 0; p < 8; ++p) {
        int w1 = p * 4 + (tid >> 6);
        int c  = tid & 63;
        X[(size_t)(n0 + w1) * CD + c0 + c] = tile[c][w1];
    }
}

// ---------------------------------------------------------------------------
// Streaming d2 partials. Grid (256, NSPLIT): blockIdx.x = b*128 + h (full-res
// row), blockIdx.y = 128-channel split. Thread (w1 = tid&31, cg = tid>>5):
// float4 y load covers the 4 w-candidates (j) of point (b,h1,w1) at channel
// c = cs*128 + k*8 + cg. 4 independent fp64 acc chains; coalesced 512B
// y segments per 32-lane group.
__global__ __launch_bounds__(256, 4)
void k_d2_partial(const float* __restrict__ x, const float* __restrict__ y,
                  double* __restrict__ d2p) {
    __shared__ double red[8][32][4];
    int bxh = blockIdx.x;
    int cs  = blockIdx.y;
    int b = bxh >> 7, h = bxh & 127;
    int h1 = h >> 2, i = h & 3;
    int tid = threadIdx.x;
    int w1 = tid & 31, cg = tid >> 5;
    int c0 = cs * 128 + cg;
    const float* yp = y + ((size_t)(b * 768 + c0) * 128 + h) * 128 + 4 * w1;
    const float* xp = x + (size_t)(b * 768 + c0) * 1024 + h1 * 32 + w1;
    double a0 = 0.0, a1 = 0.0, a2 = 0.0, a3 = 0.0;
    #pragma unroll 4
    for (int k = 0; k < 16; ++k) {
        float4 yv = *(const float4*)yp;
        float xv = *xp;
        double xd = (double)xv;
        double d0 = xd - (double)yv.x;
        double d1 = xd - (double)yv.y;
        double d2_ = xd - (double)yv.z;
        double d3 = xd - (double)yv.w;
        a0 += d0 * d0; a1 += d1 * d1; a2 += d2_ * d2_; a3 += d3 * d3;
        yp += (size_t)8 * 16384;
        xp += (size_t)8 * 1024;
    }
    red[cg][w1][0] = a0; red[cg][w1][1] = a1;
    red[cg][w1][2] = a2; red[cg][w1][3] = a3;
    __syncthreads();
    if (tid < 128) {
        int w = tid >> 2, j = tid & 3;
        double s = 0.0;
        #pragma unroll
        for (int g = 0; g < 8; ++g) s += red[g][w][j];
        int n = b * 1024 + h1 * 32 + w;
        d2p[((size_t)cs * NP + n) * 16 + i * 4 + j] = s;
    }
}

// ---------------------------------------------------------------------------
__global__ void k_argmax_gather(const double* __restrict__ d2p, const float* __restrict__ y,
                                float* __restrict__ Ysel) {
    __shared__ double sd2[16];
    __shared__ int sidx;
    int n = blockIdx.x;
    int tid = threadIdx.x;
    if (tid < 16) {
        double s = 0.0;
        #pragma unroll
        for (int cs = 0; cs < NSPLIT; ++cs) s += d2p[((size_t)cs * NP + n) * 16 + tid];
        sd2[tid] = s;
    }
    __syncthreads();
    if (tid == 0) {
        double best = sd2[0]; int bi = 0;
        #pragma unroll
        for (int k = 1; k < 16; ++k) if (sd2[k] > best) { best = sd2[k]; bi = k; }
        sidx = bi;
    }
    __syncthreads();
    int idx = sidx;
    int b = n >> 10, rem = n & 1023, h1 = rem >> 5, w1 = rem & 31;
    int row = 4 * h1 + (idx >> 2);
    int colp = 4 * w1 + (idx & 3);
    for (int c = tid; c < CD; c += 256) {
        float v = y[(size_t)(b * 768 + c) * 16384 + (size_t)row * 128 + colp];
        Ysel[(size_t)n * CD + c] = v;
    }
}

// ---------------------------------------------------------------------------
__global__ void k_row_norm(const float* __restrict__ M, float* __restrict__ out) {
    __shared__ double red[256];
    int n = blockIdx.x, tid = threadIdx.x;
    double s = 0.0;
    for (int c = tid; c < CD; c += 256) {
        float v = M[(size_t)n * CD + c];
        s += (double)v * (double)v;
    }
    red[tid] = s;
    __syncthreads();
    for (int st = 128; st > 0; st >>= 1) {
        if (tid < st) red[tid] += red[tid + st];
        __syncthreads();
    }
    if (tid == 0) out[n] = (float)red[0];
}

// ---------------------------------------------------------------------------
static __device__ inline unsigned short f2bf(float v) {
    union { float f; unsigned u; } a; a.f = v;
    unsigned r = a.u + 0x7fffu + ((a.u >> 16) & 1u);
    return (unsigned short)(r >> 16);
}
static __device__ inline float bf2f(unsigned short h) {
    union { unsigned u; float f; } a; a.u = ((unsigned)h) << 16;
    return a.f;
}
__global__ void k_pack(const float* __restrict__ X, const float* __restrict__ Ysel,
                       unsigned short* __restrict__ Xhi, unsigned short* __restrict__ Xlo,
                       unsigned short* __restrict__ Yhi, unsigned short* __restrict__ Ylo) {
    int z = blockIdx.y;
    const float* src = z ? Ysel : X;
    unsigned short* dh = z ? Yhi : Xhi;
    unsigned short* dl = z ? Ylo : Xlo;
    size_t i4 = ((size_t)blockIdx.x * 256 + threadIdx.x) * 4;
    float4 v = *(const float4*)(src + i4);
    ushort4 h, l;
    h.x = f2bf(v.x); l.x = f2bf(v.x - bf2f(h.x));
    h.y = f2bf(v.y); l.y = f2bf(v.y - bf2f(h.y));
    h.z = f2bf(v.z); l.z = f2bf(v.z - bf2f(h.z));
    h.w = f2bf(v.w); l.w = f2bf(v.w - bf2f(h.w));
    *(ushort4*)(dh + i4) = h;
    *(ushort4*)(dl + i4) = l;
}

// ---------------------------------------------------------------------------
// MFMA Gram + exp-sum. Split-bf16: K'' = 3*768, A-side = [hi|lo|hi],
// B-side = [hi|hi|lo]. Grid: 136 (XX upper-tri) + 136 (YY) + 256 (XY) = 528.
__global__ __launch_bounds__(256, 2)
void k_mmd_mfma(const unsigned short* __restrict__ Xhi, const unsigned short* __restrict__ Xlo,
                const unsigned short* __restrict__ Yhi, const unsigned short* __restrict__ Ylo,
                const float* __restrict__ a2, const float* __restrict__ b2,
                double* __restrict__ accg) {
    __shared__ unsigned short As[128 * 72];
    __shared__ unsigned short Bs[128 * 72];
    __shared__ double red[256];

    int id = blockIdx.x;
    int z, bx, by;
    double w = 1.0;
    if (id < 272) {
        z = (id < 136) ? 0 : 1;
        if (id >= 136) id -= 136;
        int r = 0;
        while (id >= 16 - r) { id -= 16 - r; ++r; }
        by = r; bx = r + id;
        if (bx != by) w = 2.0;
    } else {
        z = 2; id -= 272;
        bx = id & 15; by = id >> 4;
    }
    const unsigned short* AH = (z == 1) ? Yhi : Xhi;
    const unsigned short* AL = (z == 1) ? Ylo : Xlo;
    const unsigned short* BH = (z == 0) ? Xhi : Yhi;
    const unsigned short* BL = (z == 0) ? Xlo : Ylo;
    const float* na = (z == 1) ? b2 : a2;
    const float* nb = (z == 0) ? a2 : b2;
    int i0 = by * 128, j0 = bx * 128;

    int tid = threadIdx.x;
    int lane = tid & 63;
    int wv = tid >> 6;
    int wr = wv >> 1, wc = wv & 1;
    int m = lane & 15, q = lane >> 4;
    int srow = tid >> 3, sg = tid & 7;

    f32x4 acc[4][4] = {};

    for (int kk = 0; kk < 2304; kk += 64) {
        int p = (kk >= 1536) ? 2 : (kk >= 768 ? 1 : 0);
        int kc = kk - p * 768;
        const unsigned short* Asrc = (p == 1) ? AL : AH;
        const unsigned short* Bsrc = (p == 2) ? BL : BH;
        __syncthreads();
        #pragma unroll
        for (int s = 0; s < 4; ++s) {
            int r = s * 32 + srow;
            uint4 av = *(const uint4*)(Asrc + (size_t)(i0 + r) * CD + kc + sg * 8);
            uint4 bv = *(const uint4*)(Bsrc + (size_t)(j0 + r) * CD + kc + sg * 8);
            *(uint4*)&As[r * 72 + sg * 8] = av;
            *(uint4*)&Bs[r * 72 + sg * 8] = bv;
        }
        __syncthreads();
        #pragma unroll
        for (int s16 = 0; s16 < 2; ++s16) {
            bf16frag af[4], bg[4];
            #pragma unroll
            for (int t = 0; t < 4; ++t) {
                af[t] = *(const bf16frag*)&As[(wr * 64 + t * 16 + m) * 72 + s16 * 32 + q * 8];
                bg[t] = *(const bf16frag*)&Bs[(wc * 64 + t * 16 + m) * 72 + s16 * 32 + q * 8];
            }
            #pragma unroll
            for (int ti = 0; ti < 4; ++ti)
                #pragma unroll
                for (int tj = 0; tj < 4; ++tj)
                    acc[ti][tj] = __builtin_amdgcn_mfma_f32_16x16x32_bf16(
                        af[ti], bg[tj], acc[ti][tj], 0, 0, 0);
        }
    }

    double s = 0.0;
    #pragma unroll
    for (int ti = 0; ti < 4; ++ti) {
        #pragma unroll
        for (int r = 0; r < 4; ++r) {
            int i = i0 + wr * 64 + ti * 16 + q * 4 + r;
            float ai = na[i];
            #pragma unroll
            for (int tj = 0; tj < 4; ++tj) {
                int j = j0 + wc * 64 + tj * 16 + m;
                float d = ai + nb[j] - 2.0f * acc[ti][tj][r];
                d = fmaxf(d, 0.0f);
                s += (double)expf(-MMD_GAMMA * d);
            }
        }
    }
    red[tid] = s;
    __syncthreads();
    for (int st = 128; st > 0; st >>= 1) {
        if (tid < st) red[tid] += red[tid + st];
        __syncthreads();
    }
    if (tid == 0) atomicAdd(&accg[z], w * red[0]);
}

// ---------------------------------------------------------------------------
__global__ void k_finalize(const double* __restrict__ acc, float* __restrict__ out) {
    const double inv = 1.0 / ((double)NP * (double)NP);
    out[0] = (float)((acc[0] + acc[1] - 2.0 * acc[2]) * inv);
}

extern "C" void kernel_launch(void* const* d_in, const int* in_sizes, int n_in,
                              void* d_out, int out_size, void* d_ws, size_t ws_size,
                              hipStream_t stream) {
    const float* x = (const float*)d_in[0];
    const float* y = (const float*)d_in[1];
    float* out = (float*)d_out;

    char* ws = (char*)d_ws;
    double* acc  = (double*)ws;                       // 3 doubles
    double* d2p  = (double*)(ws + 1024);              // <= 2 MB
    float*  X    = (float*)(ws + 1024 + 2097152);
    float*  Ysel = X + (size_t)NP * CD;
    float*  a2   = Ysel + (size_t)NP * CD;
    float*  b2   = a2 + NP;
    unsigned short* Xhi = (unsigned short*)(b2 + NP);
    unsigned short* Xlo = Xhi + (size_t)NP * CD;
    unsigned short* Yhi = Xlo + (size_t)NP * CD;
    unsigned short* Ylo = Yhi + (size_t)NP * CD;

    hipMemsetAsync(acc, 0, 3 * sizeof(double), stream);
    k_transpose_x<<<dim3(64, 12), 256, 0, stream>>>(x, X);
    k_d2_partial<<<dim3(256, NSPLIT), 256, 0, stream>>>(x, y, d2p);
    k_argmax_gather<<<NP, 256, 0, stream>>>(d2p, y, Ysel);
    k_row_norm<<<NP, 256, 0, stream>>>(X, a2);
    k_row_norm<<<NP, 256, 0, stream>>>(Ysel, b2);
    k_pack<<<dim3(1536, 2), 256, 0, stream>>>(X, Ysel, Xhi, Xlo, Yhi, Ylo);
    k_mmd_mfma<<<528, 256, 0, stream>>>(Xhi, Xlo, Yhi, Ylo, a2, b2, acc);
    k_finalize<<<1, 1, 0, stream>>>(acc, out);
}

// Round 4
// 254.788 us; speedup vs baseline: 2.0555x; 1.0617x over previous
//
#include <hip/hip_runtime.h>

// Problem constants
#define NP 2048          // B*H1*W1 points
#define CD 768           // channels
#define NSPLIT 6         // channel splits for d2 partials (128 ch each)
#define MMD_GAMMA 0.00065f

typedef short bf16frag __attribute__((ext_vector_type(8)));
typedef float f32x4 __attribute__((ext_vector_type(4)));

#define GLD16(g, l)  __builtin_amdgcn_global_load_lds(                      \
    (const __attribute__((address_space(1))) void*)(g),                     \
    (__attribute__((address_space(3))) void*)(l), 16, 0, 0)

// ---------------------------------------------------------------------------
__global__ void k_transpose_x(const float* __restrict__ x, float* __restrict__ X) {
    __shared__ float tile[64][33];
    int bx = blockIdx.x;
    int c0 = blockIdx.y * 64;
    int b = bx >> 5, h1 = bx & 31;
    int tid = threadIdx.x;
    const float* src = x + (size_t)(b * 768 + c0) * 1024 + h1 * 32;
    #pragma unroll
    for (int p = 0; p < 8; ++p) {
        int cl = p * 8 + (tid >> 5);
        int w1 = tid & 31;
        tile[cl][w1] = src[(size_t)cl * 1024 + w1];
    }
    __syncthreads();
    int n0 = bx * 32;
    #pragma unroll
    for (int p = 0; p < 8; ++p) {
        int w1 = p * 4 + (tid >> 6);
        int c  = tid & 63;
        X[(size_t)(n0 + w1) * CD + c0 + c] = tile[c][w1];
    }
}

// ---------------------------------------------------------------------------
__global__ __launch_bounds__(256, 4)
void k_d2_partial(const float* __restrict__ x, const float* __restrict__ y,
                  double* __restrict__ d2p) {
    __shared__ double red[8][32][4];
    int bxh = blockIdx.x;
    int cs  = blockIdx.y;
    int b = bxh >> 7, h = bxh & 127;
    int h1 = h >> 2, i = h & 3;
    int tid = threadIdx.x;
    int w1 = tid & 31, cg = tid >> 5;
    int c0 = cs * 128 + cg;
    const float* yp = y + ((size_t)(b * 768 + c0) * 128 + h) * 128 + 4 * w1;
    const float* xp = x + (size_t)(b * 768 + c0) * 1024 + h1 * 32 + w1;
    double a0 = 0.0, a1 = 0.0, a2 = 0.0, a3 = 0.0;
    #pragma unroll 4
    for (int k = 0; k < 16; ++k) {
        float4 yv = *(const float4*)yp;
        float xv = *xp;
        double xd = (double)xv;
        double d0 = xd - (double)yv.x;
        double d1 = xd - (double)yv.y;
        double d2_ = xd - (double)yv.z;
        double d3 = xd - (double)yv.w;
        a0 += d0 * d0; a1 += d1 * d1; a2 += d2_ * d2_; a3 += d3 * d3;
        yp += (size_t)8 * 16384;
        xp += (size_t)8 * 1024;
    }
    red[cg][w1][0] = a0; red[cg][w1][1] = a1;
    red[cg][w1][2] = a2; red[cg][w1][3] = a3;
    __syncthreads();
    if (tid < 128) {
        int w = tid >> 2, j = tid & 3;
        double s = 0.0;
        #pragma unroll
        for (int g = 0; g < 8; ++g) s += red[g][w][j];
        int n = b * 1024 + h1 * 32 + w;
        d2p[((size_t)cs * NP + n) * 16 + i * 4 + j] = s;
    }
}

// ---------------------------------------------------------------------------
__global__ void k_argmax_gather(const double* __restrict__ d2p, const float* __restrict__ y,
                                float* __restrict__ Ysel) {
    __shared__ double sd2[16];
    __shared__ int sidx;
    int n = blockIdx.x;
    int tid = threadIdx.x;
    if (tid < 16) {
        double s = 0.0;
        #pragma unroll
        for (int cs = 0; cs < NSPLIT; ++cs) s += d2p[((size_t)cs * NP + n) * 16 + tid];
        sd2[tid] = s;
    }
    __syncthreads();
    if (tid == 0) {
        double best = sd2[0]; int bi = 0;
        #pragma unroll
        for (int k = 1; k < 16; ++k) if (sd2[k] > best) { best = sd2[k]; bi = k; }
        sidx = bi;
    }
    __syncthreads();
    int idx = sidx;
    int b = n >> 10, rem = n & 1023, h1 = rem >> 5, w1 = rem & 31;
    int row = 4 * h1 + (idx >> 2);
    int colp = 4 * w1 + (idx & 3);
    for (int c = tid; c < CD; c += 256) {
        float v = y[(size_t)(b * 768 + c) * 16384 + (size_t)row * 128 + colp];
        Ysel[(size_t)n * CD + c] = v;
    }
}

// ---------------------------------------------------------------------------
__global__ void k_row_norm(const float* __restrict__ M, float* __restrict__ out) {
    __shared__ double red[256];
    int n = blockIdx.x, tid = threadIdx.x;
    double s = 0.0;
    for (int c = tid; c < CD; c += 256) {
        float v = M[(size_t)n * CD + c];
        s += (double)v * (double)v;
    }
    red[tid] = s;
    __syncthreads();
    for (int st = 128; st > 0; st >>= 1) {
        if (tid < st) red[tid] += red[tid + st];
        __syncthreads();
    }
    if (tid == 0) out[n] = (float)red[0];
}

// ---------------------------------------------------------------------------
static __device__ inline unsigned short f2bf(float v) {
    union { float f; unsigned u; } a; a.f = v;
    unsigned r = a.u + 0x7fffu + ((a.u >> 16) & 1u);
    return (unsigned short)(r >> 16);
}
static __device__ inline float bf2f(unsigned short h) {
    union { unsigned u; float f; } a; a.u = ((unsigned)h) << 16;
    return a.f;
}
__global__ void k_pack(const float* __restrict__ X, const float* __restrict__ Ysel,
                       unsigned short* __restrict__ Xhi, unsigned short* __restrict__ Xlo,
                       unsigned short* __restrict__ Yhi, unsigned short* __restrict__ Ylo) {
    int z = blockIdx.y;
    const float* src = z ? Ysel : X;
    unsigned short* dh = z ? Yhi : Xhi;
    unsigned short* dl = z ? Ylo : Xlo;
    size_t i4 = ((size_t)blockIdx.x * 256 + threadIdx.x) * 4;
    float4 v = *(const float4*)(src + i4);
    ushort4 h, l;
    h.x = f2bf(v.x); l.x = f2bf(v.x - bf2f(h.x));
    h.y = f2bf(v.y); l.y = f2bf(v.y - bf2f(h.y));
    h.z = f2bf(v.z); l.z = f2bf(v.z - bf2f(h.z));
    h.w = f2bf(v.w); l.w = f2bf(v.w - bf2f(h.w));
    *(ushort4*)(dh + i4) = h;
    *(ushort4*)(dl + i4) = l;
}

// ---------------------------------------------------------------------------
// MFMA Gram + exp-sum. Split-bf16 K''=2304: A=[hi|lo|hi], B=[hi|hi|lo].
// LDS: unpadded 64-bf16 rows, XOR-swizzled 16B chunks (chunk c of row r holds
// global chunk c^(r&7)); staged via global_load_lds width=16 (1KB/wave-instr,
// wave-uniform base). Frag reads land 2-way-aliased max (free).
__global__ __launch_bounds__(256, 2)
void k_mmd_mfma(const unsigned short* __restrict__ Xhi, const unsigned short* __restrict__ Xlo,
                const unsigned short* __restrict__ Yhi, const unsigned short* __restrict__ Ylo,
                const float* __restrict__ a2, const float* __restrict__ b2,
                double* __restrict__ accg) {
    __shared__ unsigned short As[128 * 64];
    __shared__ unsigned short Bs[128 * 64];
    __shared__ float red[256];

    int id = blockIdx.x;
    int z, bx, by;
    double w = 1.0;
    if (id < 272) {
        z = (id < 136) ? 0 : 1;
        if (id >= 136) id -= 136;
        int r = 0;
        while (id >= 16 - r) { id -= 16 - r; ++r; }
        by = r; bx = r + id;
        if (bx != by) w = 2.0;
    } else {
        z = 2; id -= 272;
        bx = id & 15; by = id >> 4;
    }
    const unsigned short* AH = (z == 1) ? Yhi : Xhi;
    const unsigned short* AL = (z == 1) ? Ylo : Xlo;
    const unsigned short* BH = (z == 0) ? Xhi : Yhi;
    const unsigned short* BL = (z == 0) ? Xlo : Ylo;
    const float* na = (z == 1) ? b2 : a2;
    const float* nb = (z == 0) ? a2 : b2;
    int i0 = by * 128, j0 = bx * 128;

    int tid = threadIdx.x;
    int lane = tid & 63;
    int wv = tid >> 6;
    int wr = wv >> 1, wc = wv & 1;
    int m = lane & 15, q = lane >> 4;
    int lrow = lane >> 3, lchunk = lane & 7;   // staging: 8 rows x 8 chunks

    f32x4 acc[4][4] = {};

    for (int kk = 0; kk < 2304; kk += 64) {
        int p = (kk >= 1536) ? 2 : (kk >= 768 ? 1 : 0);
        int kc = kk - p * 768;
        const unsigned short* Asrc = (p == 1) ? AL : AH;
        const unsigned short* Bsrc = (p == 2) ? BL : BH;
        __syncthreads();
        #pragma unroll
        for (int s = 0; s < 4; ++s) {
            int r0 = s * 32 + wv * 8;          // wave-uniform row base
            int r  = r0 + lrow;
            int cg = lchunk ^ (r & 7);         // swizzled source chunk
            GLD16(Asrc + (size_t)(i0 + r) * CD + kc + cg * 8, &As[r0 * 64]);
            GLD16(Bsrc + (size_t)(j0 + r) * CD + kc + cg * 8, &Bs[r0 * 64]);
        }
        __syncthreads();
        #pragma unroll
        for (int s16 = 0; s16 < 2; ++s16) {
            bf16frag af[4], bg[4];
            #pragma unroll
            for (int t = 0; t < 4; ++t) {
                int ra = wr * 64 + t * 16 + m;
                int rb = wc * 64 + t * 16 + m;
                af[t] = *(const bf16frag*)&As[ra * 64 + ((s16 * 4 + q) ^ (m & 7)) * 8];
                bg[t] = *(const bf16frag*)&Bs[rb * 64 + ((s16 * 4 + q) ^ (m & 7)) * 8];
            }
            #pragma unroll
            for (int ti = 0; ti < 4; ++ti)
                #pragma unroll
                for (int tj = 0; tj < 4; ++tj)
                    acc[ti][tj] = __builtin_amdgcn_mfma_f32_16x16x32_bf16(
                        af[ti], bg[tj], acc[ti][tj], 0, 0, 0);
        }
    }

    float s = 0.0f;
    #pragma unroll
    for (int ti = 0; ti < 4; ++ti) {
        #pragma unroll
        for (int r = 0; r < 4; ++r) {
            int i = i0 + wr * 64 + ti * 16 + q * 4 + r;
            float ai = na[i];
            #pragma unroll
            for (int tj = 0; tj < 4; ++tj) {
                int j = j0 + wc * 64 + tj * 16 + m;
                float d = ai + nb[j] - 2.0f * acc[ti][tj][r];
                d = fmaxf(d, 0.0f);
                s += expf(-MMD_GAMMA * d);
            }
        }
    }
    red[tid] = s;
    __syncthreads();
    for (int st = 128; st > 0; st >>= 1) {
        if (tid < st) red[tid] += red[tid + st];
        __syncthreads();
    }
    if (tid == 0) atomicAdd(&accg[z], w * (double)red[0]);
}

// ---------------------------------------------------------------------------
__global__ void k_finalize(const double* __restrict__ acc, float* __restrict__ out) {
    const double inv = 1.0 / ((double)NP * (double)NP);
    out[0] = (float)((acc[0] + acc[1] - 2.0 * acc[2]) * inv);
}

extern "C" void kernel_launch(void* const* d_in, const int* in_sizes, int n_in,
                              void* d_out, int out_size, void* d_ws, size_t ws_size,
                              hipStream_t stream) {
    const float* x = (const float*)d_in[0];
    const float* y = (const float*)d_in[1];
    float* out = (float*)d_out;

    char* ws = (char*)d_ws;
    double* acc  = (double*)ws;                       // 3 doubles
    double* d2p  = (double*)(ws + 1024);              // <= 2 MB
    float*  X    = (float*)(ws + 1024 + 2097152);
    float*  Ysel = X + (size_t)NP * CD;
    float*  a2   = Ysel + (size_t)NP * CD;
    float*  b2   = a2 + NP;
    unsigned short* Xhi = (unsigned short*)(b2 + NP);
    unsigned short* Xlo = Xhi + (size_t)NP * CD;
    unsigned short* Yhi = Xlo + (size_t)NP * CD;
    unsigned short* Ylo = Yhi + (size_t)NP * CD;

    hipMemsetAsync(acc, 0, 3 * sizeof(double), stream);
    k_transpose_x<<<dim3(64, 12), 256, 0, stream>>>(x, X);
    k_d2_partial<<<dim3(256, NSPLIT), 256, 0, stream>>>(x, y, d2p);
    k_argmax_gather<<<NP, 256, 0, stream>>>(d2p, y, Ysel);
    k_row_norm<<<NP, 256, 0, stream>>>(X, a2);
    k_row_norm<<<NP, 256, 0, stream>>>(Ysel, b2);
    k_pack<<<dim3(1536, 2), 256, 0, stream>>>(X, Ysel, Xhi, Xlo, Yhi, Ylo);
    k_mmd_mfma<<<528, 256, 0, stream>>>(Xhi, Xlo, Yhi, Ylo, a2, b2, acc);
    k_finalize<<<1, 1, 0, stream>>>(acc, out);
}